// Round 12
// baseline (52.397 us; speedup 1.0000x reference)
//
#include <hip/hip_runtime.h>
#include <math.h>

#define CDIM   862
#define NRANK  8
#define KW     7
#define ROWS_PER_BLOCK 2     // 128-thread blocks -> WG-slot limit 16/CU -> up to 32 waves/CU
#define THREADS (ROWS_PER_BLOCK * 64)
#define LN_EPS 1e-5f
#define EPL    14            // elements per lane: 62 lanes cover 862 (lane 61 partial)
#define PPL    (EPL / 2)     // 7 output float2 pairs per lane
#define NQ     11            // window float2 loads per lane: x[14i-4 .. 14i+17]
#define MAXPAIR 430          // last valid float2 pair index in a row (862/2 - 1)

// One wave = one row; lane i owns elements [14i, 14i+13] from a 22-float
// register window. No LDS, no barriers, no inter-wave coupling -> extra
// resident waves convert directly into issue slots. Round 10 inner structure
// verbatim (fused per-pair compute; phase-batching regressed in round 11).
// 128-thread blocks double the per-CU wave ceiling vs 256 (8 WG cap).
__global__ __launch_bounds__(THREADS, 8) void cvmc_kernel(
    const float* __restrict__ x,
    const float* __restrict__ Wup,
    const float* __restrict__ bup,
    const float* __restrict__ Wdown,
    const float* __restrict__ bdown,
    const float* __restrict__ gamma,
    const float* __restrict__ beta,
    float* __restrict__ out)
{
    const int lane = threadIdx.x & 63;
    const int wv   = threadIdx.x >> 6;
    const int row  = blockIdx.x * ROWS_PER_BLOCK + wv;

    // Uniform weights -> SGPR scalar loads.
    float wu[NRANK][KW];
    float bu[NRANK], wd[NRANK];
#pragma unroll
    for (int r = 0; r < NRANK; ++r) {
#pragma unroll
        for (int k = 0; k < KW; ++k) wu[r][k] = Wup[r * KW + k];
        bu[r] = bup[r];
        wd[r] = Wdown[r];
    }
    const float bd = bdown[0];

    const float C1 = -0.0713548162f;   // gelu(t) ~ t*sigmoid(1.5957691 t + 0.07135482 t^3)
    const float C0 = -1.5957691216f;

    const float2* __restrict__ xp = reinterpret_cast<const float2*>(x + (size_t)row * CDIM);

    // Load the lane's 22-float window into registers (indices static after unroll).
    float w[2 * NQ];
#pragma unroll
    for (int q = 0; q < NQ; ++q) {
        int pi = 7 * lane - 2 + q;                 // float2 pair index (may be OOB)
        int pc = pi < 0 ? 0 : (pi > MAXPAIR ? MAXPAIR : pi);
        float2 v = xp[pc];
        // Left halo x[-4..-1]: lane 0, q<2. Right halo x[862..]: lane 61, q>=6.
        if (q < 2)  { if (lane == 0)  { v.x = 0.0f; v.y = 0.0f; } }
        if (q >= 6) { if (lane == 61) { v.x = 0.0f; v.y = 0.0f; } }
        w[2 * q]     = v.x;
        w[2 * q + 1] = v.y;
    }

    float2 yv[PPL];
    float sum = 0.0f, sumsq = 0.0f;

#pragma unroll
    for (int pe = 0; pe < PPL; ++pe) {
        const int ce = EPL * lane + 2 * pe;        // global element index of y0
        const bool valid = (ce < CDIM);            // pairs never split (862 even)
        const int f = 2 * pe;                      // elem0 window = w[f+1..f+7], elem1 = w[f+2..f+8]
        float acc0 = bd, acc1 = bd;
#pragma unroll
        for (int rp = 0; rp < NRANK / 2; ++rp) {
            const int ra = 2 * rp, rb = 2 * rp + 1;
            float ta0 = bu[ra], ta1 = bu[ra];
            float tb0 = bu[rb], tb1 = bu[rb];
#pragma unroll
            for (int k = 0; k < KW; ++k) {
                ta0 = fmaf(wu[ra][k], w[f + k + 1], ta0);
                ta1 = fmaf(wu[ra][k], w[f + k + 2], ta1);
                tb0 = fmaf(wu[rb][k], w[f + k + 1], tb0);
                tb1 = fmaf(wu[rb][k], w[f + k + 2], tb1);
            }
            const float za0 = ta0 * fmaf(ta0 * ta0, C1, C0);
            const float za1 = ta1 * fmaf(ta1 * ta1, C1, C0);
            const float zb0 = tb0 * fmaf(tb0 * tb0, C1, C0);
            const float zb1 = tb1 * fmaf(tb1 * tb1, C1, C0);
            const float ua0 = 1.0f + __expf(za0);
            const float ua1 = 1.0f + __expf(za1);
            const float ub0 = 1.0f + __expf(zb0);
            const float ub1 = 1.0f + __expf(zb1);
            // wd_a*t_a/u_a + wd_b*t_b/u_b = (a_a*u_b + a_b*u_a)/(u_a*u_b)
            const float r0 = __builtin_amdgcn_rcpf(ua0 * ub0);
            const float r1 = __builtin_amdgcn_rcpf(ua1 * ub1);
            const float aa0 = wd[ra] * ta0, aa1 = wd[ra] * ta1;
            const float ab0 = wd[rb] * tb0, ab1 = wd[rb] * tb1;
            float n0 = aa0 * ub0; n0 = fmaf(ab0, ua0, n0);
            float n1 = aa1 * ub1; n1 = fmaf(ab1, ua1, n1);
            acc0 = fmaf(n0, r0, acc0);
            acc1 = fmaf(n1, r1, acc1);
        }
        float y0 = w[f + 4] + acc0;   // x[ce]   + h
        float y1 = w[f + 5] + acc1;   // x[ce+1] + h
        if (!valid) { y0 = 0.0f; y1 = 0.0f; }      // tail lanes contribute 0
        yv[pe] = make_float2(y0, y1);
        sum += y0 + y1;
        sumsq = fmaf(y0, y0, sumsq);
        sumsq = fmaf(y1, y1, sumsq);
    }

    // In-wave butterfly: every lane ends with row totals. No LDS, no barrier.
#pragma unroll
    for (int off = 1; off < 64; off <<= 1) {
        sum   += __shfl_xor(sum, off, 64);
        sumsq += __shfl_xor(sumsq, off, 64);
    }

    {
        const float inv  = 1.0f / (float)CDIM;
        const float mu   = sum * inv;
        const float var  = fmaf(sumsq, inv, -mu * mu);
        const float rstd = rsqrtf(var + LN_EPS);

        float2* __restrict__ yr2 = reinterpret_cast<float2*>(out + (size_t)row * CDIM);
        const float2* __restrict__ g2 = reinterpret_cast<const float2*>(gamma);
        const float2* __restrict__ b2 = reinterpret_cast<const float2*>(beta);
#pragma unroll
        for (int pe = 0; pe < PPL; ++pe) {
            const int ce = EPL * lane + 2 * pe;
            if (ce < CDIM) {
                const int m = 7 * lane + pe;       // pair index in row
                const float2 gv = g2[m];
                const float2 bv = b2[m];
                float2 o;
                o.x = fmaf((yv[pe].x - mu) * rstd, gv.x, bv.x);
                o.y = fmaf((yv[pe].y - mu) * rstd, gv.y, bv.y);
                yr2[m] = o;
            }
        }
    }
}

extern "C" void kernel_launch(void* const* d_in, const int* in_sizes, int n_in,
                              void* d_out, int out_size, void* d_ws, size_t ws_size,
                              hipStream_t stream) {
    const float* x     = (const float*)d_in[0];
    const float* Wup   = (const float*)d_in[1];
    const float* bup   = (const float*)d_in[2];
    const float* Wdown = (const float*)d_in[3];
    const float* bdown = (const float*)d_in[4];
    const float* gamma = (const float*)d_in[5];
    const float* beta  = (const float*)d_in[6];
    float* out = (float*)d_out;

    const int nrows = out_size / CDIM;                 // 11520 (divisible by 2)
    const int nblk  = nrows / ROWS_PER_BLOCK;          // 5760
    cvmc_kernel<<<nblk, THREADS, 0, stream>>>(x, Wup, bup, Wdown, bdown,
                                              gamma, beta, out);
}

// Round 13
// 41.167 us; speedup vs baseline: 1.2728x; 1.2728x over previous
//
#include <hip/hip_runtime.h>
#include <math.h>

#define CDIM   862
#define NRANK  8
#define KW     7
#define ROWS_PER_BLOCK 4
#define THREADS (ROWS_PER_BLOCK * 64)
#define LN_EPS 1e-5f
#define EPL    14            // elements per lane: 62 lanes cover 862 (lane 61 partial)
#define PPL    (EPL / 2)     // 7 output float2 pairs per lane
#define NQ     11            // window float2 loads per lane: x[14i-4 .. 14i+17]
#define MAXPAIR 430          // last valid float2 pair index in a row (862/2 - 1)

typedef float f2 __attribute__((ext_vector_type(2)));

static __device__ __forceinline__ f2 fma2(f2 a, f2 b, f2 c) {
    return __builtin_elementwise_fma(a, b, c);
}
static __device__ __forceinline__ f2 splat(float s) { f2 v; v.x = s; v.y = s; return v; }

// One wave = one row; lane i owns elements [14i, 14i+13] from a 22-float
// register window (no LDS, no barriers) -- round 10 structure. THIS ROUND:
// the e0/e1 element pair is computed on <2 x float> vectors so the backend
// emits packed VOP3P f32 ops (v_pk_fma_f32 etc., 2 f32/lane per 2-cy
// instruction -- the 157 TF vs 78.6 TF scalar fp32 factor). Per-component
// arithmetic order is bit-identical to round 10 -> absmax must stay 0.03125.
// Only exp/rcp remain scalar (trans pipe has no packed form).
__global__ __launch_bounds__(THREADS) void cvmc_kernel(
    const float* __restrict__ x,
    const float* __restrict__ Wup,
    const float* __restrict__ bup,
    const float* __restrict__ Wdown,
    const float* __restrict__ bdown,
    const float* __restrict__ gamma,
    const float* __restrict__ beta,
    float* __restrict__ out)
{
    const int lane = threadIdx.x & 63;
    const int wv   = threadIdx.x >> 6;
    const int row  = blockIdx.x * ROWS_PER_BLOCK + wv;

    // Uniform weights -> SGPR scalar loads.
    float wu[NRANK][KW];
    float bu[NRANK], wd[NRANK];
#pragma unroll
    for (int r = 0; r < NRANK; ++r) {
#pragma unroll
        for (int k = 0; k < KW; ++k) wu[r][k] = Wup[r * KW + k];
        bu[r] = bup[r];
        wd[r] = Wdown[r];
    }
    const float bd = bdown[0];

    const f2 C1 = splat(-0.0713548162f);   // gelu(t) ~ t*sigmoid(1.5957691 t + 0.07135482 t^3)
    const f2 C0 = splat(-1.5957691216f);

    const float2* __restrict__ xp = reinterpret_cast<const float2*>(x + (size_t)row * CDIM);

    // Load the lane's 22-float window into registers (indices static after unroll).
    float w[2 * NQ];
#pragma unroll
    for (int q = 0; q < NQ; ++q) {
        int pi = 7 * lane - 2 + q;                 // float2 pair index (may be OOB)
        int pc = pi < 0 ? 0 : (pi > MAXPAIR ? MAXPAIR : pi);
        float2 v = xp[pc];
        // Left halo x[-4..-1]: lane 0, q<2. Right halo x[862..]: lane 61, q>=6.
        if (q < 2)  { if (lane == 0)  { v.x = 0.0f; v.y = 0.0f; } }
        if (q >= 6) { if (lane == 61) { v.x = 0.0f; v.y = 0.0f; } }
        w[2 * q]     = v.x;
        w[2 * q + 1] = v.y;
    }

    f2 yv[PPL];
    float sum = 0.0f, sumsq = 0.0f;

#pragma unroll
    for (int pe = 0; pe < PPL; ++pe) {
        const int ce = EPL * lane + 2 * pe;        // global element index of y0
        const bool valid = (ce < CDIM);            // pairs never split (862 even)
        const int f = 2 * pe;                      // elem0 window = w[f+1..f+7], elem1 = w[f+2..f+8]

        // Packed conv-window operand: b2[k] = (w[f+k+1], w[f+k+2]).
        f2 b2[KW];
#pragma unroll
        for (int k = 0; k < KW; ++k) { b2[k].x = w[f + k + 1]; b2[k].y = w[f + k + 2]; }

        // Conv: 8 packed accumulator chains (one per rank, e0/e1 in lanes).
        f2 t2[NRANK];
#pragma unroll
        for (int r = 0; r < NRANK; ++r) t2[r] = splat(bu[r]);
#pragma unroll
        for (int r = 0; r < NRANK; ++r) {
#pragma unroll
            for (int k = 0; k < KW; ++k) {
                t2[r] = fma2(splat(wu[r][k]), b2[k], t2[r]);
            }
        }

        // GELU sigmoid arg + exp (exp is scalar trans; everything else packed).
        f2 u2[NRANK];
#pragma unroll
        for (int r = 0; r < NRANK; ++r) {
            const f2 t = t2[r];
            const f2 z = t * fma2(t * t, C1, C0);
            f2 u;
            u.x = 1.0f + __expf(z.x);
            u.y = 1.0f + __expf(z.y);
            u2[r] = u;
        }

        // Rank-paired rcp + combine (same component order as round 10).
        f2 acc2 = splat(bd);
#pragma unroll
        for (int rp = 0; rp < NRANK / 2; ++rp) {
            const int ra = 2 * rp, rb = 2 * rp + 1;
            const f2 uu = u2[ra] * u2[rb];
            f2 rr;
            rr.x = __builtin_amdgcn_rcpf(uu.x);
            rr.y = __builtin_amdgcn_rcpf(uu.y);
            const f2 aa = splat(wd[ra]) * t2[ra];
            const f2 ab = splat(wd[rb]) * t2[rb];
            f2 n = aa * u2[rb];
            n = fma2(ab, u2[ra], n);
            acc2 = fma2(n, rr, acc2);
        }

        f2 y2;
        y2.x = w[f + 4] + acc2.x;     // x[ce]   + h
        y2.y = w[f + 5] + acc2.y;     // x[ce+1] + h
        if (!valid) { y2.x = 0.0f; y2.y = 0.0f; }  // tail lanes contribute 0
        yv[pe] = y2;
        sum += y2.x + y2.y;
        sumsq = fmaf(y2.x, y2.x, sumsq);
        sumsq = fmaf(y2.y, y2.y, sumsq);
    }

    // In-wave butterfly: every lane ends with row totals. No LDS, no barrier.
#pragma unroll
    for (int off = 1; off < 64; off <<= 1) {
        sum   += __shfl_xor(sum, off, 64);
        sumsq += __shfl_xor(sumsq, off, 64);
    }

    {
        const float inv  = 1.0f / (float)CDIM;
        const float mu   = sum * inv;
        const float var  = fmaf(sumsq, inv, -mu * mu);
        const float rstd = rsqrtf(var + LN_EPS);

        float2* __restrict__ yr2 = reinterpret_cast<float2*>(out + (size_t)row * CDIM);
        const float2* __restrict__ g2 = reinterpret_cast<const float2*>(gamma);
        const float2* __restrict__ b2p = reinterpret_cast<const float2*>(beta);
#pragma unroll
        for (int pe = 0; pe < PPL; ++pe) {
            const int ce = EPL * lane + 2 * pe;
            if (ce < CDIM) {
                const int m = 7 * lane + pe;       // pair index in row
                const float2 gv = g2[m];
                const float2 bv = b2p[m];
                float2 o;
                o.x = fmaf((yv[pe].x - mu) * rstd, gv.x, bv.x);
                o.y = fmaf((yv[pe].y - mu) * rstd, gv.y, bv.y);
                yr2[m] = o;
            }
        }
    }
}

extern "C" void kernel_launch(void* const* d_in, const int* in_sizes, int n_in,
                              void* d_out, int out_size, void* d_ws, size_t ws_size,
                              hipStream_t stream) {
    const float* x     = (const float*)d_in[0];
    const float* Wup   = (const float*)d_in[1];
    const float* bup   = (const float*)d_in[2];
    const float* Wdown = (const float*)d_in[3];
    const float* bdown = (const float*)d_in[4];
    const float* gamma = (const float*)d_in[5];
    const float* beta  = (const float*)d_in[6];
    float* out = (float*)d_out;

    const int nrows = out_size / CDIM;                 // 11520 (divisible by 4)
    const int nblk  = nrows / ROWS_PER_BLOCK;          // 2880
    cvmc_kernel<<<nblk, THREADS, 0, stream>>>(x, Wup, bup, Wdown, bdown,
                                              gamma, beta, out);
}